// Round 3
// baseline (276.520 us; speedup 1.0000x reference)
//
#include <hip/hip_runtime.h>

#define B_    64
#define C_    2048
#define HW_   288
#define EPS_  0.07f
#define TINY_ 1e-8f

// ---------------------------------------------------------------------------
// Kernel 1: per-token partial sums, one C-chunk per WAVE. nch=32 chunks.
// grid = B * nch/4 = 512 blocks, 256 threads (4 waves; wave wid owns chunk
// cg*4+wid, cpc=64 rows). Lane l accumulates h = 4l..4l+3 (float4) plus tail
// h = 256+4l..4l+3 for lanes 0..7. Fully coalesced float4 loads/stores.
// part layout: [3 planes][B*nch][288]  (7.1 MB total).
// ---------------------------------------------------------------------------
__device__ __forceinline__ void acc3(const float4 v, float a0, float a1,
                                     float* ssq, float* sd0, float* sd1) {
  ssq[0] += v.x * v.x; ssq[1] += v.y * v.y; ssq[2] += v.z * v.z; ssq[3] += v.w * v.w;
  sd0[0] += v.x * a0;  sd0[1] += v.y * a0;  sd0[2] += v.z * a0;  sd0[3] += v.w * a0;
  sd1[0] += v.x * a1;  sd1[1] += v.y * a1;  sd1[2] += v.z * a1;  sd1[3] += v.w * a1;
}

__global__ __launch_bounds__(256) void k1_partials(
    const float* __restrict__ x, const float* __restrict__ anchors,
    float* __restrict__ part, int nch, int cpc) {
  int bi = blockIdx.x;
  int nblk = nch >> 2;            // chunk-groups per b
  int b  = bi / nblk;
  int cg = bi - b * nblk;
  int t = threadIdx.x, lane = t & 63, wid = t >> 6;
  int ch = cg * 4 + wid;          // this wave's chunk
  int c0 = ch * cpc;
  const float* xb = x + ((size_t)b * C_ + c0) * HW_;
  bool tail = lane < 8;

  float ssq[4] = {0,0,0,0}, sd0[4] = {0,0,0,0}, sd1[4] = {0,0,0,0};
  float tsq[4] = {0,0,0,0}, td0[4] = {0,0,0,0}, td1[4] = {0,0,0,0};

#pragma unroll 4
  for (int r = 0; r < cpc; ++r) {
    const float4* xr = (const float4*)(xb + (size_t)r * HW_);
    float a0 = anchors[c0 + r];
    float a1 = anchors[C_ + c0 + r];
    float4 xa = xr[lane];
    acc3(xa, a0, a1, ssq, sd0, sd1);
    if (tail) {
      float4 xc = xr[64 + lane];
      acc3(xc, a0, a1, tsq, td0, td1);
    }
  }

  size_t PS = (size_t)B_ * nch * HW_;
  float* base = part + (size_t)(b * nch + ch) * HW_;
  float4* p0 = (float4*)base;
  float4* p1 = (float4*)(base + PS);
  float4* p2 = (float4*)(base + 2 * PS);
  p0[lane] = make_float4(ssq[0], ssq[1], ssq[2], ssq[3]);
  p1[lane] = make_float4(sd0[0], sd0[1], sd0[2], sd0[3]);
  p2[lane] = make_float4(sd1[0], sd1[1], sd1[2], sd1[3]);
  if (tail) {
    p0[64 + lane] = make_float4(tsq[0], tsq[1], tsq[2], tsq[3]);
    p1[64 + lane] = make_float4(td0[0], td0[1], td0[2], td0[3]);
    p2[64 + lane] = make_float4(td1[0], td1[1], td1[2], td1[3]);
  }
}

// ---------------------------------------------------------------------------
// Kernel 1b: collapse nch chunk-partials -> red[3][B][288]. 216 blocks.
// ---------------------------------------------------------------------------
__global__ __launch_bounds__(256) void k1b_reduce(
    const float* __restrict__ part, float* __restrict__ red, int nch) {
  int idx = blockIdx.x * 256 + threadIdx.x;       // < 3*64*288 = 55296
  int plane = idx / (B_ * HW_);
  int rem = idx - plane * (B_ * HW_);
  int b = rem / HW_;
  int h = rem - b * HW_;
  const float* p = part + (size_t)plane * B_ * nch * HW_ + (size_t)b * nch * HW_ + h;
  float s = 0.f;
#pragma unroll 8
  for (int ch = 0; ch < nch; ++ch) s += p[(size_t)ch * HW_];
  red[idx] = s;
}

// Block-wide 2-value sum reduction for 320 threads (5 full waves).
__device__ __forceinline__ void block_reduce2(
    float& p0, float& p1, volatile float* red0, volatile float* red1,
    int t, int nw) {
  int lane = t & 63, wid = t >> 6;
#pragma unroll
  for (int off = 32; off >= 1; off >>= 1) {
    p0 += __shfl_down(p0, off);
    p1 += __shfl_down(p1, off);
  }
  __syncthreads();
  if (lane == 0) { red0[wid] = p0; red1[wid] = p1; }
  __syncthreads();
  float s0 = 0.f, s1 = 0.f;
  for (int w = 0; w < nw; ++w) { s0 += red0[w]; s1 += red1[w]; }
  p0 = s0; p1 = s1;
}

// ---------------------------------------------------------------------------
// Kernel 2: per-batch Sinkhorn. grid = 64 blocks, 320 threads.
// ---------------------------------------------------------------------------
__global__ __launch_bounds__(320) void k2_sinkhorn(
    const float* __restrict__ red, const float* __restrict__ anchors,
    float* __restrict__ out_m, float* __restrict__ invden) {
  int b = blockIdx.x, t = threadIdx.x;
  __shared__ float red0[8], red1[8];
  const int nw = 5;

  float a0 = 0.f, a1 = 0.f;
  for (int c = t; c < C_; c += 320) {
    float q0 = anchors[c], q1 = anchors[C_ + c];
    a0 += q0 * q0; a1 += q1 * q1;
  }
  block_reduce2(a0, a1, red0, red1, t, nw);
  float ian0 = 1.0f / fmaxf(sqrtf(a0), 1e-12f);
  float ian1 = 1.0f / fmaxf(sqrtf(a1), 1e-12f);

  float K0 = 0.f, K1 = 0.f;
  if (t < HW_) {
    float ssq = red[b * HW_ + t];
    float d0  = red[B_ * HW_ + b * HW_ + t];
    float d1  = red[2 * B_ * HW_ + b * HW_ + t];
    float ixn = 1.0f / fmaxf(sqrtf(ssq), 1e-12f);
    float cos0 = d0 * ixn * ian0;
    float cos1 = d1 * ixn * ian1;
    K0 = expf((cos0 - 1.0f) / EPS_) + TINY_;
    K1 = expf((cos1 - 1.0f) / EPS_) + TINY_;
  }

  float v0 = 1.f, v1 = 1.f, u = 0.f;
  for (int it = 0; it < 7; ++it) {
    if (t < HW_) u = (1.0f / (float)HW_) / (K0 * v0 + K1 * v1 + TINY_);
    float p0 = K0 * u, p1 = K1 * u;
    block_reduce2(p0, p1, red0, red1, t, nw);
    v0 = 0.5f / (p0 + TINY_);
    v1 = 0.5f / (p1 + TINY_);
  }

  float m0 = 0.f, m1 = 0.f;
  if (t < HW_) {
    m0 = K0 * u * v0 * (float)HW_;
    m1 = K1 * u * v1 * (float)HW_;
  }
  float q0 = m0, q1 = m1;
  block_reduce2(q0, q1, red0, red1, t, nw);
  if (t < HW_) {
    out_m[(b * 2 + 0) * HW_ + t] = m0;
    out_m[(b * 2 + 1) * HW_ + t] = m1;
  }
  if (t == 0) {
    invden[b * 2 + 0] = 1.0f / (q0 + 1e-6f);
    invden[b * 2 + 1] = 1.0f / (q1 + 1e-6f);
  }
}

// ---------------------------------------------------------------------------
// Kernel 3: masked pooling, register-resident mask fragments.
// 8 threads per c-row; thread's octant `oct` owns h-positions oct*9..oct*9+8
// (9 contiguous float4). w0[9]/w1[9] depend only on h-position -> loaded ONCE
// into registers, reused across all 256 rows the block handles. Inner loop is
// pure global-load + FMA (no LDS). Row combine: 3 shfl_xor pairs.
// grid = B*8 = 512 blocks, 256 threads (block covers 256 c-rows).
// ---------------------------------------------------------------------------
__global__ __launch_bounds__(256) void k3_pool(
    const float* __restrict__ x, const float* __restrict__ m,
    const float* __restrict__ invden, float* __restrict__ out) {
  int bi = blockIdx.x;
  int b = bi >> 3, seg = bi & 7;
  int t = threadIdx.x, oct = t & 7, rl = t >> 3;   // rl = 0..31

  const float4* m0 = (const float4*)(m + (b * 2 + 0) * HW_);
  const float4* m1 = (const float4*)(m + (b * 2 + 1) * HW_);
  float4 w0[9], w1[9];
#pragma unroll
  for (int j = 0; j < 9; ++j) {
    w0[j] = m0[oct * 9 + j];
    w1[j] = m1[oct * 9 + j];
  }
  float inv0 = invden[2 * b], inv1 = invden[2 * b + 1];

  int cbase = seg * 256;
#pragma unroll 2
  for (int g = 0; g < 8; ++g) {
    int c = cbase + g * 32 + rl;
    const float4* xr = (const float4*)(x + ((size_t)b * C_ + c) * HW_) + oct * 9;
    float a0 = 0.f, a1 = 0.f;
#pragma unroll
    for (int j = 0; j < 9; ++j) {
      float4 xa = xr[j];
      a0 += xa.x * w0[j].x + xa.y * w0[j].y + xa.z * w0[j].z + xa.w * w0[j].w;
      a1 += xa.x * w1[j].x + xa.y * w1[j].y + xa.z * w1[j].z + xa.w * w1[j].w;
    }
#pragma unroll
    for (int off = 4; off >= 1; off >>= 1) {
      a0 += __shfl_xor(a0, off);
      a1 += __shfl_xor(a1, off);
    }
    if (oct == 0) {
      out[(size_t)b * C_ + c] = a0 * inv0;
      out[(size_t)B_ * C_ + (size_t)b * C_ + c] = a1 * inv1;
    }
  }
}

extern "C" void kernel_launch(void* const* d_in, const int* in_sizes, int n_in,
                              void* d_out, int out_size, void* d_ws, size_t ws_size,
                              hipStream_t stream) {
  const float* x       = (const float*)d_in[0];
  const float* anchors = (const float*)d_in[1];
  float* out = (float*)d_out;

  // ws layout: invden[128] | red[3*64*288] | part[3*B*nch*288]
  float* invden = (float*)d_ws;
  float* red = invden + 128;
  float* part = red + 3 * B_ * HW_;
  int nch = 32;
  while (nch > 4 &&
         (size_t)(128 + 3 * B_ * HW_ + 3 * B_ * nch * HW_) * sizeof(float) > ws_size)
    nch >>= 1;
  int cpc = C_ / nch;

  float* out_m = out + 2 * B_ * C_;  // m region of d_out (B,2,H,W)

  k1_partials<<<B_ * (nch / 4), 256, 0, stream>>>(x, anchors, part, nch, cpc);
  k1b_reduce<<<(3 * B_ * HW_) / 256, 256, 0, stream>>>(part, red, nch);
  k2_sinkhorn<<<B_, 320, 0, stream>>>(red, anchors, out_m, invden);
  k3_pool<<<B_ * 8, 256, 0, stream>>>(x, out_m, invden, out);
}

// Round 4
// 251.926 us; speedup vs baseline: 1.0976x; 1.0976x over previous
//
#include <hip/hip_runtime.h>

#define B_    64
#define C_    2048
#define HW_   288
#define EPS_  0.07f
#define TINY_ 1e-8f
#define NCH_  64
#define CPC_  (C_ / NCH_)   // 32 rows per chunk

// ---------------------------------------------------------------------------
// Kernel 1: per-token partial sums, one C-chunk per WAVE, two-phase.
// grid = B*NCH/4 = 1024 blocks, 256 threads (4 waves; wave wid owns chunk
// cg*4+wid, CPC=32 rows).
// Main phase: lane l owns float4 #l of each row (h=4l..4l+3); depth-4
// explicit load pipeline keeps 4 KB/wave in flight.
// Tail phase: row float4s 64..71; lane l handles row k*8+(l>>3), q=64+(l&7);
// 3-step shfl_xor combine over the 8 row-groups.
// part layout: [3 planes][B*NCH][288] (14.2 MB).
// ---------------------------------------------------------------------------
__device__ __forceinline__ void acc3(const float4 v, float a0, float a1,
                                     float* ssq, float* sd0, float* sd1) {
  ssq[0] += v.x * v.x; ssq[1] += v.y * v.y; ssq[2] += v.z * v.z; ssq[3] += v.w * v.w;
  sd0[0] += v.x * a0;  sd0[1] += v.y * a0;  sd0[2] += v.z * a0;  sd0[3] += v.w * a0;
  sd1[0] += v.x * a1;  sd1[1] += v.y * a1;  sd1[2] += v.z * a1;  sd1[3] += v.w * a1;
}

__global__ __launch_bounds__(256) void k1_partials(
    const float* __restrict__ x, const float* __restrict__ anchors,
    float* __restrict__ part) {
  int bi = blockIdx.x;
  int b  = bi >> 4;                // NCH/4 = 16 chunk-groups per b
  int cg = bi & 15;
  int t = threadIdx.x, lane = t & 63, wid = t >> 6;
  int ch = cg * 4 + wid;
  int c0 = ch * CPC_;
  const float* xb = x + ((size_t)b * C_ + c0) * HW_;

  float ssq[4] = {0,0,0,0}, sd0[4] = {0,0,0,0}, sd1[4] = {0,0,0,0};

  // ---- main phase: depth-4 pipelined 64-lane row reads ----
  float4 buf[4];
#pragma unroll
  for (int j = 0; j < 4; ++j)
    buf[j] = ((const float4*)(xb + (size_t)j * HW_))[lane];

#pragma unroll 1
  for (int r = 0; r < CPC_; r += 4) {
    float4 cur[4];
#pragma unroll
    for (int j = 0; j < 4; ++j) cur[j] = buf[j];
    if (r + 4 < CPC_) {
#pragma unroll
      for (int j = 0; j < 4; ++j)
        buf[j] = ((const float4*)(xb + (size_t)(r + 4 + j) * HW_))[lane];
    }
#pragma unroll
    for (int j = 0; j < 4; ++j) {
      float a0 = anchors[c0 + r + j];
      float a1 = anchors[C_ + c0 + r + j];
      acc3(cur[j], a0, a1, ssq, sd0, sd1);
    }
  }

  // ---- tail phase: q = 64 + (lane&7), rows k*8 + (lane>>3) ----
  float tsq[4] = {0,0,0,0}, td0[4] = {0,0,0,0}, td1[4] = {0,0,0,0};
  int rg = lane >> 3, q = lane & 7;
#pragma unroll
  for (int k = 0; k < CPC_ / 8; ++k) {
    int r = k * 8 + rg;
    float4 v = ((const float4*)(xb + (size_t)r * HW_))[64 + q];
    float a0 = anchors[c0 + r];
    float a1 = anchors[C_ + c0 + r];
    acc3(v, a0, a1, tsq, td0, td1);
  }
#pragma unroll
  for (int off = 8; off < 64; off <<= 1) {
#pragma unroll
    for (int j = 0; j < 4; ++j) {
      tsq[j] += __shfl_xor(tsq[j], off);
      td0[j] += __shfl_xor(td0[j], off);
      td1[j] += __shfl_xor(td1[j], off);
    }
  }

  size_t PS = (size_t)B_ * NCH_ * HW_;
  float* base = part + (size_t)(b * NCH_ + ch) * HW_;
  ((float4*)base)[lane]          = make_float4(ssq[0], ssq[1], ssq[2], ssq[3]);
  ((float4*)(base + PS))[lane]   = make_float4(sd0[0], sd0[1], sd0[2], sd0[3]);
  ((float4*)(base + 2*PS))[lane] = make_float4(sd1[0], sd1[1], sd1[2], sd1[3]);
  if (lane < 8) {
    ((float4*)base)[64 + lane]          = make_float4(tsq[0], tsq[1], tsq[2], tsq[3]);
    ((float4*)(base + PS))[64 + lane]   = make_float4(td0[0], td0[1], td0[2], td0[3]);
    ((float4*)(base + 2*PS))[64 + lane] = make_float4(td1[0], td1[1], td1[2], td1[3]);
  }
}

// ---------------------------------------------------------------------------
// Kernel 1b: collapse NCH chunk-partials -> red[3][B][288]. 216 blocks.
// ---------------------------------------------------------------------------
__global__ __launch_bounds__(256) void k1b_reduce(
    const float* __restrict__ part, float* __restrict__ red) {
  int idx = blockIdx.x * 256 + threadIdx.x;       // < 3*64*288 = 55296
  int plane = idx / (B_ * HW_);
  int rem = idx - plane * (B_ * HW_);
  int b = rem / HW_;
  int h = rem - b * HW_;
  const float* p = part + (size_t)plane * B_ * NCH_ * HW_ + (size_t)b * NCH_ * HW_ + h;
  float s = 0.f;
#pragma unroll 8
  for (int ch = 0; ch < NCH_; ++ch) s += p[(size_t)ch * HW_];
  red[idx] = s;
}

// Block-wide 2-value sum reduction for 320 threads (5 full waves).
__device__ __forceinline__ void block_reduce2(
    float& p0, float& p1, volatile float* red0, volatile float* red1,
    int t, int nw) {
  int lane = t & 63, wid = t >> 6;
#pragma unroll
  for (int off = 32; off >= 1; off >>= 1) {
    p0 += __shfl_down(p0, off);
    p1 += __shfl_down(p1, off);
  }
  __syncthreads();
  if (lane == 0) { red0[wid] = p0; red1[wid] = p1; }
  __syncthreads();
  float s0 = 0.f, s1 = 0.f;
  for (int w = 0; w < nw; ++w) { s0 += red0[w]; s1 += red1[w]; }
  p0 = s0; p1 = s1;
}

// ---------------------------------------------------------------------------
// Kernel 2: per-batch Sinkhorn. grid = 64 blocks, 320 threads.
// ---------------------------------------------------------------------------
__global__ __launch_bounds__(320) void k2_sinkhorn(
    const float* __restrict__ red, const float* __restrict__ anchors,
    float* __restrict__ out_m, float* __restrict__ invden) {
  int b = blockIdx.x, t = threadIdx.x;
  __shared__ float red0[8], red1[8];
  const int nw = 5;

  float a0 = 0.f, a1 = 0.f;
  for (int c = t; c < C_; c += 320) {
    float q0 = anchors[c], q1 = anchors[C_ + c];
    a0 += q0 * q0; a1 += q1 * q1;
  }
  block_reduce2(a0, a1, red0, red1, t, nw);
  float ian0 = 1.0f / fmaxf(sqrtf(a0), 1e-12f);
  float ian1 = 1.0f / fmaxf(sqrtf(a1), 1e-12f);

  float K0 = 0.f, K1 = 0.f;
  if (t < HW_) {
    float ssq = red[b * HW_ + t];
    float d0  = red[B_ * HW_ + b * HW_ + t];
    float d1  = red[2 * B_ * HW_ + b * HW_ + t];
    float ixn = 1.0f / fmaxf(sqrtf(ssq), 1e-12f);
    float cos0 = d0 * ixn * ian0;
    float cos1 = d1 * ixn * ian1;
    K0 = expf((cos0 - 1.0f) / EPS_) + TINY_;
    K1 = expf((cos1 - 1.0f) / EPS_) + TINY_;
  }

  float v0 = 1.f, v1 = 1.f, u = 0.f;
  for (int it = 0; it < 7; ++it) {
    if (t < HW_) u = (1.0f / (float)HW_) / (K0 * v0 + K1 * v1 + TINY_);
    float p0 = K0 * u, p1 = K1 * u;
    block_reduce2(p0, p1, red0, red1, t, nw);
    v0 = 0.5f / (p0 + TINY_);
    v1 = 0.5f / (p1 + TINY_);
  }

  float m0 = 0.f, m1 = 0.f;
  if (t < HW_) {
    m0 = K0 * u * v0 * (float)HW_;
    m1 = K1 * u * v1 * (float)HW_;
  }
  float q0 = m0, q1 = m1;
  block_reduce2(q0, q1, red0, red1, t, nw);
  if (t < HW_) {
    out_m[(b * 2 + 0) * HW_ + t] = m0;
    out_m[(b * 2 + 1) * HW_ + t] = m1;
  }
  if (t == 0) {
    invden[b * 2 + 0] = 1.0f / (q0 + 1e-6f);
    invden[b * 2 + 1] = 1.0f / (q1 + 1e-6f);
  }
}

// ---------------------------------------------------------------------------
// Kernel 3: masked pooling, register-resident mask fragments, batched loads.
// 8 threads per c-row; octant `oct` owns 9 contiguous float4 of the row.
// w0[9]/w1[9] loaded once into registers, reused across 128 rows. Inner body:
// 9 batched global loads, then 18 dot FMA groups, then 3 shfl_xor pairs.
// grid = B*16 = 1024 blocks (4 blocks/CU), 256 threads, 4 row-groups each.
// ---------------------------------------------------------------------------
__global__ __launch_bounds__(256) void k3_pool(
    const float* __restrict__ x, const float* __restrict__ m,
    const float* __restrict__ invden, float* __restrict__ out) {
  int bi = blockIdx.x;
  int b = bi >> 4, seg = bi & 15;
  int t = threadIdx.x, oct = t & 7, rl = t >> 3;   // rl = 0..31

  const float4* m0 = (const float4*)(m + (b * 2 + 0) * HW_);
  const float4* m1 = (const float4*)(m + (b * 2 + 1) * HW_);
  float4 w0[9], w1[9];
#pragma unroll
  for (int j = 0; j < 9; ++j) {
    w0[j] = m0[oct * 9 + j];
    w1[j] = m1[oct * 9 + j];
  }
  float inv0 = invden[2 * b], inv1 = invden[2 * b + 1];

  int cbase = seg * 128;
#pragma unroll 1
  for (int g = 0; g < 4; ++g) {
    int c = cbase + g * 32 + rl;
    const float4* xr = (const float4*)(x + ((size_t)b * C_ + c) * HW_) + oct * 9;
    float4 xa[9];
#pragma unroll
    for (int j = 0; j < 9; ++j) xa[j] = xr[j];
    float a0 = 0.f, a1 = 0.f;
#pragma unroll
    for (int j = 0; j < 9; ++j) {
      a0 += xa[j].x * w0[j].x + xa[j].y * w0[j].y + xa[j].z * w0[j].z + xa[j].w * w0[j].w;
      a1 += xa[j].x * w1[j].x + xa[j].y * w1[j].y + xa[j].z * w1[j].z + xa[j].w * w1[j].w;
    }
#pragma unroll
    for (int off = 4; off >= 1; off >>= 1) {
      a0 += __shfl_xor(a0, off);
      a1 += __shfl_xor(a1, off);
    }
    if (oct == 0) {
      out[(size_t)b * C_ + c] = a0 * inv0;
      out[(size_t)B_ * C_ + (size_t)b * C_ + c] = a1 * inv1;
    }
  }
}

extern "C" void kernel_launch(void* const* d_in, const int* in_sizes, int n_in,
                              void* d_out, int out_size, void* d_ws, size_t ws_size,
                              hipStream_t stream) {
  const float* x       = (const float*)d_in[0];
  const float* anchors = (const float*)d_in[1];
  float* out = (float*)d_out;

  // ws layout: invden[128] | red[3*64*288] | part[3*B*NCH*288]  (~14.4 MB)
  float* invden = (float*)d_ws;
  float* red = invden + 128;
  float* part = red + 3 * B_ * HW_;

  float* out_m = out + 2 * B_ * C_;  // m region of d_out (B,2,H,W)

  k1_partials<<<B_ * (NCH_ / 4), 256, 0, stream>>>(x, anchors, part);
  k1b_reduce<<<(3 * B_ * HW_) / 256, 256, 0, stream>>>(part, red);
  k2_sinkhorn<<<B_, 320, 0, stream>>>(red, anchors, out_m, invden);
  k3_pool<<<B_ * 16, 256, 0, stream>>>(x, out_m, invden, out);
}

// Round 5
// 249.771 us; speedup vs baseline: 1.1071x; 1.0086x over previous
//
#include <hip/hip_runtime.h>

#define B_    64
#define C_    2048
#define HW_   288
#define EPS_  0.07f
#define TINY_ 1e-8f
#define NCH_  64
#define CPC_  (C_ / NCH_)   // 32 rows per chunk

__device__ __forceinline__ float comp(const float4 v, int i) {
  return i == 0 ? v.x : i == 1 ? v.y : i == 2 ? v.z : v.w;
}

__device__ __forceinline__ void acc3(const float4 v, float a0, float a1,
                                     float* ssq, float* sd0, float* sd1) {
  ssq[0] += v.x * v.x; ssq[1] += v.y * v.y; ssq[2] += v.z * v.z; ssq[3] += v.w * v.w;
  sd0[0] += v.x * a0;  sd0[1] += v.y * a0;  sd0[2] += v.z * a0;  sd0[3] += v.w * a0;
  sd1[0] += v.x * a1;  sd1[1] += v.y * a1;  sd1[2] += v.z * a1;  sd1[3] += v.w * a1;
}

// ---------------------------------------------------------------------------
// Kernel 1: per-token partial sums, one C-chunk per WAVE, two-phase, with
// BOTH x-rows and anchors flowing through a depth-1-group (4-row) double-
// buffered pipeline: inner group issues 4 x float4 loads + 2 anchor float4
// loads for group g+1, then computes group g (waits vmcnt(6), never 0).
// Main phase: lane l owns float4 #l of each row (h=4l..4l+3).
// Tail phase: batched prefetch of all 12 tail loads, then compute + 3-step
// shfl_xor combine. part layout: [3 planes][B*NCH][288] (14.2 MB).
// grid = B*NCH/4 = 1024 blocks, 256 threads (4 waves/block).
// ---------------------------------------------------------------------------
__global__ __launch_bounds__(256) void k1_partials(
    const float* __restrict__ x, const float* __restrict__ anchors,
    float* __restrict__ part) {
  int bi = blockIdx.x;
  int b  = bi >> 4;                // NCH/4 = 16 chunk-groups per b
  int cg = bi & 15;
  int t = threadIdx.x, lane = t & 63, wid = t >> 6;
  int ch = cg * 4 + wid;
  int c0 = ch * CPC_;
  const float* xb = x + ((size_t)b * C_ + c0) * HW_;
  const float4* a0v = (const float4*)(anchors + c0);        // 16B-aligned: c0 % 32 == 0
  const float4* a1v = (const float4*)(anchors + C_ + c0);

  float ssq[4] = {0,0,0,0}, sd0[4] = {0,0,0,0}, sd1[4] = {0,0,0,0};

  // ---- main phase: double-buffered 4-row groups (x + anchors together) ----
  float4 xbuf[4], abuf0, abuf1;
#pragma unroll
  for (int j = 0; j < 4; ++j)
    xbuf[j] = ((const float4*)(xb + (size_t)j * HW_))[lane];
  abuf0 = a0v[0];
  abuf1 = a1v[0];

#pragma unroll 1
  for (int r = 0; r < CPC_; r += 4) {
    float4 xcur[4], ac0 = abuf0, ac1 = abuf1;
#pragma unroll
    for (int j = 0; j < 4; ++j) xcur[j] = xbuf[j];
    if (r + 4 < CPC_) {
#pragma unroll
      for (int j = 0; j < 4; ++j)
        xbuf[j] = ((const float4*)(xb + (size_t)(r + 4 + j) * HW_))[lane];
      abuf0 = a0v[(r >> 2) + 1];
      abuf1 = a1v[(r >> 2) + 1];
    }
#pragma unroll
    for (int j = 0; j < 4; ++j)
      acc3(xcur[j], comp(ac0, j), comp(ac1, j), ssq, sd0, sd1);
  }

  // ---- tail phase: h float4s 64..71; lane covers row k*8+(l>>3), q=l&7 ----
  int rg = lane >> 3, q = lane & 7;
  float4 tv[4];
  float ta0[4], ta1[4];
#pragma unroll
  for (int k = 0; k < CPC_ / 8; ++k) {
    int r = k * 8 + rg;
    tv[k]  = ((const float4*)(xb + (size_t)r * HW_))[64 + q];
    ta0[k] = anchors[c0 + r];
    ta1[k] = anchors[C_ + c0 + r];
  }
  float tsq[4] = {0,0,0,0}, td0[4] = {0,0,0,0}, td1[4] = {0,0,0,0};
#pragma unroll
  for (int k = 0; k < CPC_ / 8; ++k)
    acc3(tv[k], ta0[k], ta1[k], tsq, td0, td1);
#pragma unroll
  for (int off = 8; off < 64; off <<= 1) {
#pragma unroll
    for (int j = 0; j < 4; ++j) {
      tsq[j] += __shfl_xor(tsq[j], off);
      td0[j] += __shfl_xor(td0[j], off);
      td1[j] += __shfl_xor(td1[j], off);
    }
  }

  size_t PS = (size_t)B_ * NCH_ * HW_;
  float* base = part + (size_t)(b * NCH_ + ch) * HW_;
  ((float4*)base)[lane]          = make_float4(ssq[0], ssq[1], ssq[2], ssq[3]);
  ((float4*)(base + PS))[lane]   = make_float4(sd0[0], sd0[1], sd0[2], sd0[3]);
  ((float4*)(base + 2*PS))[lane] = make_float4(sd1[0], sd1[1], sd1[2], sd1[3]);
  if (lane < 8) {
    ((float4*)base)[64 + lane]          = make_float4(tsq[0], tsq[1], tsq[2], tsq[3]);
    ((float4*)(base + PS))[64 + lane]   = make_float4(td0[0], td0[1], td0[2], td0[3]);
    ((float4*)(base + 2*PS))[64 + lane] = make_float4(td1[0], td1[1], td1[2], td1[3]);
  }
}

// ---------------------------------------------------------------------------
// Kernel 1b: collapse NCH chunk-partials -> red[3][B][288]. 216 blocks.
// ---------------------------------------------------------------------------
__global__ __launch_bounds__(256) void k1b_reduce(
    const float* __restrict__ part, float* __restrict__ red) {
  int idx = blockIdx.x * 256 + threadIdx.x;       // < 3*64*288 = 55296
  int plane = idx / (B_ * HW_);
  int rem = idx - plane * (B_ * HW_);
  int b = rem / HW_;
  int h = rem - b * HW_;
  const float* p = part + (size_t)plane * B_ * NCH_ * HW_ + (size_t)b * NCH_ * HW_ + h;
  float s = 0.f;
#pragma unroll 8
  for (int ch = 0; ch < NCH_; ++ch) s += p[(size_t)ch * HW_];
  red[idx] = s;
}

// Block-wide 2-value sum reduction for 320 threads (5 full waves).
__device__ __forceinline__ void block_reduce2(
    float& p0, float& p1, volatile float* red0, volatile float* red1,
    int t, int nw) {
  int lane = t & 63, wid = t >> 6;
#pragma unroll
  for (int off = 32; off >= 1; off >>= 1) {
    p0 += __shfl_down(p0, off);
    p1 += __shfl_down(p1, off);
  }
  __syncthreads();
  if (lane == 0) { red0[wid] = p0; red1[wid] = p1; }
  __syncthreads();
  float s0 = 0.f, s1 = 0.f;
  for (int w = 0; w < nw; ++w) { s0 += red0[w]; s1 += red1[w]; }
  p0 = s0; p1 = s1;
}

// ---------------------------------------------------------------------------
// Kernel 2: per-batch Sinkhorn. grid = 64 blocks, 320 threads.
// ---------------------------------------------------------------------------
__global__ __launch_bounds__(320) void k2_sinkhorn(
    const float* __restrict__ red, const float* __restrict__ anchors,
    float* __restrict__ out_m, float* __restrict__ invden) {
  int b = blockIdx.x, t = threadIdx.x;
  __shared__ float red0[8], red1[8];
  const int nw = 5;

  float a0 = 0.f, a1 = 0.f;
  for (int c = t; c < C_; c += 320) {
    float q0 = anchors[c], q1 = anchors[C_ + c];
    a0 += q0 * q0; a1 += q1 * q1;
  }
  block_reduce2(a0, a1, red0, red1, t, nw);
  float ian0 = 1.0f / fmaxf(sqrtf(a0), 1e-12f);
  float ian1 = 1.0f / fmaxf(sqrtf(a1), 1e-12f);

  float K0 = 0.f, K1 = 0.f;
  if (t < HW_) {
    float ssq = red[b * HW_ + t];
    float d0  = red[B_ * HW_ + b * HW_ + t];
    float d1  = red[2 * B_ * HW_ + b * HW_ + t];
    float ixn = 1.0f / fmaxf(sqrtf(ssq), 1e-12f);
    float cos0 = d0 * ixn * ian0;
    float cos1 = d1 * ixn * ian1;
    K0 = expf((cos0 - 1.0f) / EPS_) + TINY_;
    K1 = expf((cos1 - 1.0f) / EPS_) + TINY_;
  }

  float v0 = 1.f, v1 = 1.f, u = 0.f;
  for (int it = 0; it < 7; ++it) {
    if (t < HW_) u = (1.0f / (float)HW_) / (K0 * v0 + K1 * v1 + TINY_);
    float p0 = K0 * u, p1 = K1 * u;
    block_reduce2(p0, p1, red0, red1, t, nw);
    v0 = 0.5f / (p0 + TINY_);
    v1 = 0.5f / (p1 + TINY_);
  }

  float m0 = 0.f, m1 = 0.f;
  if (t < HW_) {
    m0 = K0 * u * v0 * (float)HW_;
    m1 = K1 * u * v1 * (float)HW_;
  }
  float q0 = m0, q1 = m1;
  block_reduce2(q0, q1, red0, red1, t, nw);
  if (t < HW_) {
    out_m[(b * 2 + 0) * HW_ + t] = m0;
    out_m[(b * 2 + 1) * HW_ + t] = m1;
  }
  if (t == 0) {
    invden[b * 2 + 0] = 1.0f / (q0 + 1e-6f);
    invden[b * 2 + 1] = 1.0f / (q1 + 1e-6f);
  }
}

// ---------------------------------------------------------------------------
// Kernel 3: masked pooling, register-resident mask fragments, batched loads.
// 8 threads per c-row; octant `oct` owns 9 contiguous float4 of the row.
// grid = B*16 = 1024 blocks, 256 threads, 4 row-groups each.
// ---------------------------------------------------------------------------
__global__ __launch_bounds__(256) void k3_pool(
    const float* __restrict__ x, const float* __restrict__ m,
    const float* __restrict__ invden, float* __restrict__ out) {
  int bi = blockIdx.x;
  int b = bi >> 4, seg = bi & 15;
  int t = threadIdx.x, oct = t & 7, rl = t >> 3;   // rl = 0..31

  const float4* m0 = (const float4*)(m + (b * 2 + 0) * HW_);
  const float4* m1 = (const float4*)(m + (b * 2 + 1) * HW_);
  float4 w0[9], w1[9];
#pragma unroll
  for (int j = 0; j < 9; ++j) {
    w0[j] = m0[oct * 9 + j];
    w1[j] = m1[oct * 9 + j];
  }
  float inv0 = invden[2 * b], inv1 = invden[2 * b + 1];

  int cbase = seg * 128;
#pragma unroll 1
  for (int g = 0; g < 4; ++g) {
    int c = cbase + g * 32 + rl;
    const float4* xr = (const float4*)(x + ((size_t)b * C_ + c) * HW_) + oct * 9;
    float4 xa[9];
#pragma unroll
    for (int j = 0; j < 9; ++j) xa[j] = xr[j];
    float a0 = 0.f, a1 = 0.f;
#pragma unroll
    for (int j = 0; j < 9; ++j) {
      a0 += xa[j].x * w0[j].x + xa[j].y * w0[j].y + xa[j].z * w0[j].z + xa[j].w * w0[j].w;
      a1 += xa[j].x * w1[j].x + xa[j].y * w1[j].y + xa[j].z * w1[j].z + xa[j].w * w1[j].w;
    }
#pragma unroll
    for (int off = 4; off >= 1; off >>= 1) {
      a0 += __shfl_xor(a0, off);
      a1 += __shfl_xor(a1, off);
    }
    if (oct == 0) {
      out[(size_t)b * C_ + c] = a0 * inv0;
      out[(size_t)B_ * C_ + (size_t)b * C_ + c] = a1 * inv1;
    }
  }
}

extern "C" void kernel_launch(void* const* d_in, const int* in_sizes, int n_in,
                              void* d_out, int out_size, void* d_ws, size_t ws_size,
                              hipStream_t stream) {
  const float* x       = (const float*)d_in[0];
  const float* anchors = (const float*)d_in[1];
  float* out = (float*)d_out;

  // ws layout: invden[128] | red[3*64*288] | part[3*B*NCH*288]  (~14.4 MB)
  float* invden = (float*)d_ws;
  float* red = invden + 128;
  float* part = red + 3 * B_ * HW_;

  float* out_m = out + 2 * B_ * C_;  // m region of d_out (B,2,H,W)

  k1_partials<<<B_ * (NCH_ / 4), 256, 0, stream>>>(x, anchors, part);
  k1b_reduce<<<(3 * B_ * HW_) / 256, 256, 0, stream>>>(part, red);
  k2_sinkhorn<<<B_, 320, 0, stream>>>(red, anchors, out_m, invden);
  k3_pool<<<B_ * 16, 256, 0, stream>>>(x, out_m, invden, out);
}

// Round 7
// 249.699 us; speedup vs baseline: 1.1074x; 1.0003x over previous
//
#include <hip/hip_runtime.h>

#define B_    64
#define C_    2048
#define HW_   288
#define EPS_  0.07f
#define TINY_ 1e-8f
#define NCH_  64
#define CPC_  (C_ / NCH_)   // 32 rows per chunk

__device__ __forceinline__ float comp(const float4 v, int i) {
  return i == 0 ? v.x : i == 1 ? v.y : i == 2 ? v.z : v.w;
}

__device__ __forceinline__ void acc3(const float4 v, float a0, float a1,
                                     float* ssq, float* sd0, float* sd1) {
  ssq[0] += v.x * v.x; ssq[1] += v.y * v.y; ssq[2] += v.z * v.z; ssq[3] += v.w * v.w;
  sd0[0] += v.x * a0;  sd0[1] += v.y * a0;  sd0[2] += v.z * a0;  sd0[3] += v.w * a0;
  sd1[0] += v.x * a1;  sd1[1] += v.y * a1;  sd1[2] += v.z * a1;  sd1[3] += v.w * a1;
}

// ---------------------------------------------------------------------------
// Kernel 1 (R5-proven): per-token partial sums, one C-chunk per WAVE,
// x-rows AND anchors double-buffered in 4-row groups.
// grid = B*NCH/4 = 1024 blocks, 256 threads.
// part layout: [3 planes][B*NCH][288] (14.2 MB).
// ---------------------------------------------------------------------------
__global__ __launch_bounds__(256) void k1_partials(
    const float* __restrict__ x, const float* __restrict__ anchors,
    float* __restrict__ part) {
  int bi = blockIdx.x;
  int b  = bi >> 4;                // NCH/4 = 16 chunk-groups per b
  int cg = bi & 15;
  int t = threadIdx.x, lane = t & 63, wid = t >> 6;
  int ch = cg * 4 + wid;
  int c0 = ch * CPC_;
  const float* xb = x + ((size_t)b * C_ + c0) * HW_;
  const float4* a0v = (const float4*)(anchors + c0);        // c0 % 32 == 0
  const float4* a1v = (const float4*)(anchors + C_ + c0);

  float ssq[4] = {0,0,0,0}, sd0[4] = {0,0,0,0}, sd1[4] = {0,0,0,0};

  float4 xbuf[4], abuf0, abuf1;
#pragma unroll
  for (int j = 0; j < 4; ++j)
    xbuf[j] = ((const float4*)(xb + (size_t)j * HW_))[lane];
  abuf0 = a0v[0];
  abuf1 = a1v[0];

#pragma unroll 1
  for (int r = 0; r < CPC_; r += 4) {
    float4 xcur[4], ac0 = abuf0, ac1 = abuf1;
#pragma unroll
    for (int j = 0; j < 4; ++j) xcur[j] = xbuf[j];
    if (r + 4 < CPC_) {
#pragma unroll
      for (int j = 0; j < 4; ++j)
        xbuf[j] = ((const float4*)(xb + (size_t)(r + 4 + j) * HW_))[lane];
      abuf0 = a0v[(r >> 2) + 1];
      abuf1 = a1v[(r >> 2) + 1];
    }
#pragma unroll
    for (int j = 0; j < 4; ++j)
      acc3(xcur[j], comp(ac0, j), comp(ac1, j), ssq, sd0, sd1);
  }

  // tail: h float4s 64..71 (one 128B line per row); rows k*8+(lane>>3)
  int rg = lane >> 3, q = lane & 7;
  float4 tv[4];
  float ta0[4], ta1[4];
#pragma unroll
  for (int k = 0; k < CPC_ / 8; ++k) {
    int r = k * 8 + rg;
    tv[k]  = ((const float4*)(xb + (size_t)r * HW_))[64 + q];
    ta0[k] = anchors[c0 + r];
    ta1[k] = anchors[C_ + c0 + r];
  }
  float tsq[4] = {0,0,0,0}, td0[4] = {0,0,0,0}, td1[4] = {0,0,0,0};
#pragma unroll
  for (int k = 0; k < CPC_ / 8; ++k)
    acc3(tv[k], ta0[k], ta1[k], tsq, td0, td1);
#pragma unroll
  for (int off = 8; off < 64; off <<= 1) {
#pragma unroll
    for (int j = 0; j < 4; ++j) {
      tsq[j] += __shfl_xor(tsq[j], off);
      td0[j] += __shfl_xor(td0[j], off);
      td1[j] += __shfl_xor(td1[j], off);
    }
  }

  size_t PS = (size_t)B_ * NCH_ * HW_;
  float* base = part + (size_t)(b * NCH_ + ch) * HW_;
  ((float4*)base)[lane]          = make_float4(ssq[0], ssq[1], ssq[2], ssq[3]);
  ((float4*)(base + PS))[lane]   = make_float4(sd0[0], sd0[1], sd0[2], sd0[3]);
  ((float4*)(base + 2*PS))[lane] = make_float4(sd1[0], sd1[1], sd1[2], sd1[3]);
  if (lane < 8) {
    ((float4*)base)[64 + lane]          = make_float4(tsq[0], tsq[1], tsq[2], tsq[3]);
    ((float4*)(base + PS))[64 + lane]   = make_float4(td0[0], td0[1], td0[2], td0[3]);
    ((float4*)(base + 2*PS))[64 + lane] = make_float4(td1[0], td1[1], td1[2], td1[3]);
  }
}

// Block-wide 2-value sum reduction for 320 threads (5 full waves).
__device__ __forceinline__ void block_reduce2(
    float& p0, float& p1, volatile float* red0, volatile float* red1,
    int t, int nw) {
  int lane = t & 63, wid = t >> 6;
#pragma unroll
  for (int off = 32; off >= 1; off >>= 1) {
    p0 += __shfl_down(p0, off);
    p1 += __shfl_down(p1, off);
  }
  __syncthreads();
  if (lane == 0) { red0[wid] = p0; red1[wid] = p1; }
  __syncthreads();
  float s0 = 0.f, s1 = 0.f;
  for (int w = 0; w < nw; ++w) { s0 += red0[w]; s1 += red1[w]; }
  p0 = s0; p1 = s1;
}

// ---------------------------------------------------------------------------
// Kernel 2: chunk-collapse + per-batch Sinkhorn fused. grid = 64 blocks,
// 320 threads. Token t sums its 3 stats over NCH chunk-partials directly
// from `part` (coalesced across t within each chunk; L2-resident), then runs
// the 7 Sinkhorn iterations. m -> d_out, 1/den -> ws.
// ---------------------------------------------------------------------------
__global__ __launch_bounds__(320) void k2_sinkhorn(
    const float* __restrict__ part, const float* __restrict__ anchors,
    float* __restrict__ out_m, float* __restrict__ invden) {
  int b = blockIdx.x, t = threadIdx.x;
  __shared__ float red0[8], red1[8];
  const int nw = 5;

  float a0 = 0.f, a1 = 0.f;
  for (int c = t; c < C_; c += 320) {
    float q0 = anchors[c], q1 = anchors[C_ + c];
    a0 += q0 * q0; a1 += q1 * q1;
  }
  block_reduce2(a0, a1, red0, red1, t, nw);
  float ian0 = 1.0f / fmaxf(sqrtf(a0), 1e-12f);
  float ian1 = 1.0f / fmaxf(sqrtf(a1), 1e-12f);

  float K0 = 0.f, K1 = 0.f;
  if (t < HW_) {
    size_t PS = (size_t)B_ * NCH_ * HW_;
    const float* p = part + (size_t)b * NCH_ * HW_ + t;
    float ssq = 0.f, d0 = 0.f, d1 = 0.f;
#pragma unroll 8
    for (int ch = 0; ch < NCH_; ++ch) {
      size_t o = (size_t)ch * HW_;
      ssq += p[o];
      d0  += p[PS + o];
      d1  += p[2 * PS + o];
    }
    float ixn = 1.0f / fmaxf(sqrtf(ssq), 1e-12f);
    K0 = expf((d0 * ixn * ian0 - 1.0f) / EPS_) + TINY_;
    K1 = expf((d1 * ixn * ian1 - 1.0f) / EPS_) + TINY_;
  }

  float v0 = 1.f, v1 = 1.f, u = 0.f;
  for (int it = 0; it < 7; ++it) {
    if (t < HW_) u = (1.0f / (float)HW_) / (K0 * v0 + K1 * v1 + TINY_);
    float p0 = K0 * u, p1 = K1 * u;
    block_reduce2(p0, p1, red0, red1, t, nw);
    v0 = 0.5f / (p0 + TINY_);
    v1 = 0.5f / (p1 + TINY_);
  }

  float m0 = 0.f, m1 = 0.f;
  if (t < HW_) {
    m0 = K0 * u * v0 * (float)HW_;
    m1 = K1 * u * v1 * (float)HW_;
  }
  float q0 = m0, q1 = m1;
  block_reduce2(q0, q1, red0, red1, t, nw);
  if (t < HW_) {
    out_m[(b * 2 + 0) * HW_ + t] = m0;
    out_m[(b * 2 + 1) * HW_ + t] = m1;
  }
  if (t == 0) {
    invden[b * 2 + 0] = 1.0f / (q0 + 1e-6f);
    invden[b * 2 + 1] = 1.0f / (q1 + 1e-6f);
  }
}

// ---------------------------------------------------------------------------
// Kernel 3: masked pooling. TRANSACTION-COALESCED octant mapping: for load
// index j, octant `oct` reads float4 (oct + 8*j) — the 8 octs of a row cover
// ONE contiguous 128B line per instruction (was 8 scattered lines with the
// oct*9+j map). Mask fragments w[j]=m[oct+8j] stay register-resident across
// all 128 rows. Row combine: 3 shfl_xor pairs.
// grid = B*16 = 1024 blocks, 256 threads, 4 row-groups each.
// ---------------------------------------------------------------------------
__global__ __launch_bounds__(256) void k3_pool(
    const float* __restrict__ x, const float* __restrict__ m,
    const float* __restrict__ invden, float* __restrict__ out) {
  int bi = blockIdx.x;
  int b = bi >> 4, seg = bi & 15;
  int t = threadIdx.x, oct = t & 7, rl = t >> 3;   // rl = 0..31

  const float4* m0 = (const float4*)(m + (b * 2 + 0) * HW_);
  const float4* m1 = (const float4*)(m + (b * 2 + 1) * HW_);
  float4 w0[9], w1[9];
#pragma unroll
  for (int j = 0; j < 9; ++j) {
    w0[j] = m0[oct + 8 * j];
    w1[j] = m1[oct + 8 * j];
  }
  float inv0 = invden[2 * b], inv1 = invden[2 * b + 1];

  int cbase = seg * 128;
#pragma unroll 1
  for (int g = 0; g < 4; ++g) {
    int c = cbase + g * 32 + rl;
    const float4* xr = (const float4*)(x + ((size_t)b * C_ + c) * HW_);
    float4 xa[9];
#pragma unroll
    for (int j = 0; j < 9; ++j) xa[j] = xr[oct + 8 * j];
    float a0 = 0.f, a1 = 0.f;
#pragma unroll
    for (int j = 0; j < 9; ++j) {
      a0 += xa[j].x * w0[j].x + xa[j].y * w0[j].y + xa[j].z * w0[j].z + xa[j].w * w0[j].w;
      a1 += xa[j].x * w1[j].x + xa[j].y * w1[j].y + xa[j].z * w1[j].z + xa[j].w * w1[j].w;
    }
#pragma unroll
    for (int off = 4; off >= 1; off >>= 1) {
      a0 += __shfl_xor(a0, off);
      a1 += __shfl_xor(a1, off);
    }
    if (oct == 0) {
      out[(size_t)b * C_ + c] = a0 * inv0;
      out[(size_t)B_ * C_ + (size_t)b * C_ + c] = a1 * inv1;
    }
  }
}

extern "C" void kernel_launch(void* const* d_in, const int* in_sizes, int n_in,
                              void* d_out, int out_size, void* d_ws, size_t ws_size,
                              hipStream_t stream) {
  const float* x       = (const float*)d_in[0];
  const float* anchors = (const float*)d_in[1];
  float* out = (float*)d_out;

  // ws layout: invden[128] | part[3*B*NCH*288]  (~14.2 MB)
  float* invden = (float*)d_ws;
  float* part = invden + 128;

  float* out_m = out + 2 * B_ * C_;  // m region of d_out (B,2,H,W)

  k1_partials<<<B_ * (NCH_ / 4), 256, 0, stream>>>(x, anchors, part);
  k2_sinkhorn<<<B_, 320, 0, stream>>>(part, anchors, out_m, invden);
  k3_pool<<<B_ * 16, 256, 0, stream>>>(x, out_m, invden, out);
}